// Round 14
// baseline (273.261 us; speedup 1.0000x reference)
//
#include <hip/hip_runtime.h>
#include <hip/hip_bf16.h>
#include <stdint.h>

#define D_MODEL 1024
#define NHEAD   16
#define HDIM    64
#define SEQ     2048
#define BH      64   // 4 batches * 16 heads

typedef short bf16x8 __attribute__((ext_vector_type(8)));
typedef float f32x4  __attribute__((ext_vector_type(4)));

static __device__ __forceinline__ float bf2f(ushort u) {
    union { uint32_t i; float f; } v; v.i = ((uint32_t)u) << 16; return v.f;
}
static __device__ __forceinline__ ushort f2bf(float f) {
    __hip_bfloat16 h = __float2bfloat16(f);
    union { __hip_bfloat16 h; ushort u; } v; v.h = h; return v.u;
}
static __device__ __forceinline__ uint32_t pk2(float a, float b) {
    return (uint32_t)f2bf(a) | ((uint32_t)f2bf(b) << 16);
}
// Raw v_exp_f32 (2^x), single VALU op — NOT libm exp2f (ocml multi-inst).
static __device__ __forceinline__ float ex2(float x) {
    return __builtin_amdgcn_exp2f(x);
}
// Nested for v_max3_f32 fusion.
static __device__ __forceinline__ float max4(float a, float b, float c, float d) {
    return fmaxf(fmaxf(fmaxf(a, b), c), d);
}
// Async global->LDS DMA, 16B per lane; lds dest must be wave-uniform.
static __device__ __forceinline__ void gl_lds16(const ushort* g, ushort* l) {
    __builtin_amdgcn_global_load_lds(
        (const __attribute__((address_space(1))) uint32_t*)g,
        (__attribute__((address_space(3))) uint32_t*)l, 16, 0, 0);
}

// ---------------------------------------------------------------------------
// fp32 -> bf16 pre-convert (RNE), 8 elems/thread. Three source buffers fused
// into one launch (block ranges: X | Wqkv | Wout).
// ---------------------------------------------------------------------------
__global__ __launch_bounds__(256)
void cvt_k(const float* __restrict__ s0, ushort* __restrict__ d0,
           const float* __restrict__ s1, ushort* __restrict__ d1,
           const float* __restrict__ s2, ushort* __restrict__ d2)
{
    int blk = blockIdx.x;
    const float* src; ushort* dst;
    if (blk < 4096)      { src = s0; dst = d0; }
    else if (blk < 5632) { src = s1; dst = d1; blk -= 4096; }
    else                 { src = s2; dst = d2; blk -= 5632; }
    const size_t i = ((size_t)blk * 256 + threadIdx.x) * 8;
    float4 a = *(const float4*)&src[i];
    float4 b = *(const float4*)&src[i + 4];
    uint4 o;
    o.x = pk2(a.x, a.y);
    o.y = pk2(a.z, a.w);
    o.z = pk2(b.x, b.y);
    o.w = pk2(b.z, b.w);
    *(uint4*)&dst[i] = o;
}

// ---------------------------------------------------------------------------
// GEMM1: qkv = Xb[8192,1024](bf16) * Wb[3072,1024](bf16)^T.
// Staging via global_load_lds DMA, XOR-swizzled unpadded 64-stride rows.
// XCD-swizzled block mapping (m-panel-grouped). RoPE fused in epilogue (r14).
// r16: q pre-scale folds log2(e) => attn softmax in log2 domain.
// r18: q stored TRANSPOSED [bh][d][s].
// r20: RoPE epilogue via angle-addition recurrence — 1 sincos per (ni,mi)
// plus 3 exact rotations (cs'=cs*cf-sn*sf) instead of 4 sincos; cf/sf
// (sincos of freq) CSE'd across mi. 64 -> 20 sincos per thread.
// ---------------------------------------------------------------------------
__global__ __launch_bounds__(256)
void gemm_qkv(const ushort* __restrict__ Xb, const ushort* __restrict__ Wb,
              ushort* __restrict__ qt, ushort* __restrict__ kb,
              ushort* __restrict__ vt)
{
    __shared__ ushort As[128 * 64];
    __shared__ ushort Bs[128 * 64];
    const int K = 1024;
    const int lid = blockIdx.x + blockIdx.y * 24;
    const int nl  = (lid & 7) * 192 + (lid >> 3);
    const int n0 = (nl % 24) * 128;
    const int m0 = (nl / 24) * 128;
    const int t = threadIdx.x;
    const int lane = t & 63, wv = t >> 6;
    const int wm = (wv >> 1) * 64, wn = (wv & 1) * 64;
    const int l15 = lane & 15, quad = lane >> 4;

    const int rsub = lane >> 3;
    const int cg   = (lane & 7) ^ rsub;            // swizzled global chunk
    const int x7  = l15 & 7;
    const int rdk[2] = { ((quad ^ x7) * 8), (((quad + 4) ^ x7) * 8) };

    f32x4 acc[4][4];
#pragma unroll
    for (int i = 0; i < 4; i++)
#pragma unroll
        for (int j = 0; j < 4; j++) acc[i][j] = (f32x4){0.f, 0.f, 0.f, 0.f};

    for (int k0 = 0; k0 < K; k0 += 64) {
        __syncthreads();
#pragma unroll
        for (int i = 0; i < 4; i++) {
            const int rbase = i * 32 + wv * 8;
            gl_lds16(&Xb[(size_t)(m0 + rbase + rsub) * K + k0 + cg * 8], &As[rbase * 64]);
            gl_lds16(&Wb[(size_t)(n0 + rbase + rsub) * K + k0 + cg * 8], &Bs[rbase * 64]);
        }
        __syncthreads();
#pragma unroll
        for (int ks = 0; ks < 2; ks++) {
            bf16x8 af[4], bfr[4];
#pragma unroll
            for (int mi = 0; mi < 4; mi++)
                af[mi] = *(const bf16x8*)&As[(wm + mi * 16 + l15) * 64 + rdk[ks]];
#pragma unroll
            for (int ni = 0; ni < 4; ni++)
                bfr[ni] = *(const bf16x8*)&Bs[(wn + ni * 16 + l15) * 64 + rdk[ks]];
#pragma unroll
            for (int ni = 0; ni < 4; ni++)
#pragma unroll
                for (int mi = 0; mi < 4; mi++)
                    acc[mi][ni] = __builtin_amdgcn_mfma_f32_16x16x32_bf16(
                        af[mi], bfr[ni], acc[mi][ni], 0, 0, 0);
        }
    }

#pragma unroll
    for (int ni = 0; ni < 4; ni++) {
        const int e = n0 + wn + ni * 16 + l15;
        const int which = e >> 10;     // block-uniform (tiles don't straddle)
        const int h = (e >> 6) & 15;
        const int d = e & 63;
#pragma unroll
        for (int mi = 0; mi < 4; mi++) {
            const int gm0 = m0 + wm + mi * 16 + quad * 4;
            const int b = gm0 >> 11;
            const int s0 = gm0 & 2047;
            const int bh = b * NHEAD + h;
            if (which == 2) {
                ushort4 pk;
                pk.x = f2bf(acc[mi][ni][0]); pk.y = f2bf(acc[mi][ni][1]);
                pk.z = f2bf(acc[mi][ni][2]); pk.w = f2bf(acc[mi][ni][3]);
                *(ushort4*)&vt[((size_t)bh * HDIM + d) * SEQ + s0] = pk;
            } else {
                // RoPE: freq = 10000^{-(d>>1)/32}; partner x[d^1] from lane^1.
                const float freq = __expf(-(float)(d >> 1) * (9.2103403719761836f / 32.0f));
                const float sgn = (d & 1) ? 1.0f : -1.0f;
                float cf, sf;                       // sincos(freq) — CSE'd per d
                __sincosf(freq, &sf, &cf);
                float sn, cs;                       // sincos(s0*freq), advanced by r
                __sincosf((float)s0 * freq, &sn, &cs);
                float o[4];
#pragma unroll
                for (int r = 0; r < 4; r++) {
                    const float v = acc[mi][ni][r];
                    const float p = __shfl_xor(v, 1);
                    o[r] = v * cs + sgn * p * sn;
                    const float cs2 = cs * cf - sn * sf;   // exact rotation by freq
                    sn = sn * cf + cs * sf;
                    cs = cs2;
                }
                if (which == 0) {
                    // q: 1/sqrt(64)*log2(e) folded; transposed [bh][d][s] store.
                    ushort4 pk;
                    pk.x = f2bf(o[0] * 0.18033688f); pk.y = f2bf(o[1] * 0.18033688f);
                    pk.z = f2bf(o[2] * 0.18033688f); pk.w = f2bf(o[3] * 0.18033688f);
                    *(ushort4*)&qt[((size_t)bh * HDIM + d) * SEQ + s0] = pk;
                } else {
#pragma unroll
                    for (int r = 0; r < 4; r++)
                        kb[((size_t)bh * SEQ + s0 + r) * HDIM + d] = f2bf(o[r]);
                }
            }
        }
    }
}

// ---------------------------------------------------------------------------
// GEMM2: out(f32) = A[8192,1024](bf16) * Wb[1024,1024](bf16)^T — DMA staging.
// r20: tile 128x128 -> 64x128. Old grid was 512 blocks = 2 blocks/CU
// (grid-starved, 8 waves/CU); now 1024 blocks = 4/CU, LDS 24KB. Per-wave
// acc[2][4], A staged with 2 DMA issues. XCD-swizzled (chunk of 128).
// ---------------------------------------------------------------------------
__global__ __launch_bounds__(256)
void gemm_out(const ushort* __restrict__ A, const ushort* __restrict__ Wb,
              float* __restrict__ out)
{
    __shared__ ushort As[64 * 64];
    __shared__ ushort Bs[128 * 64];
    const int K = 1024;
    const int lid = blockIdx.x + blockIdx.y * 8;       // 1024 blocks
    const int nl  = (lid & 7) * 128 + (lid >> 3);      // XCD chunk of 128
    const int n0 = (nl & 7) * 128;
    const int m0 = (nl >> 3) * 64;
    const int t = threadIdx.x;
    const int lane = t & 63, wv = t >> 6;
    const int wm = (wv >> 1) * 32, wn = (wv & 1) * 64;
    const int l15 = lane & 15, quad = lane >> 4;

    const int rsub = lane >> 3;
    const int cg   = (lane & 7) ^ rsub;
    const int x7  = l15 & 7;
    const int rdk[2] = { ((quad ^ x7) * 8), (((quad + 4) ^ x7) * 8) };

    f32x4 acc[2][4];
#pragma unroll
    for (int i = 0; i < 2; i++)
#pragma unroll
        for (int j = 0; j < 4; j++) acc[i][j] = (f32x4){0.f, 0.f, 0.f, 0.f};

    for (int k0 = 0; k0 < K; k0 += 64) {
        __syncthreads();
#pragma unroll
        for (int i = 0; i < 2; i++) {
            const int rbase = i * 32 + wv * 8;
            gl_lds16(&A[(size_t)(m0 + rbase + rsub) * K + k0 + cg * 8], &As[rbase * 64]);
        }
#pragma unroll
        for (int i = 0; i < 4; i++) {
            const int rbase = i * 32 + wv * 8;
            gl_lds16(&Wb[(size_t)(n0 + rbase + rsub) * K + k0 + cg * 8], &Bs[rbase * 64]);
        }
        __syncthreads();
#pragma unroll
        for (int ks = 0; ks < 2; ks++) {
            bf16x8 af[2], bfr[4];
#pragma unroll
            for (int mi = 0; mi < 2; mi++)
                af[mi] = *(const bf16x8*)&As[(wm + mi * 16 + l15) * 64 + rdk[ks]];
#pragma unroll
            for (int ni = 0; ni < 4; ni++)
                bfr[ni] = *(const bf16x8*)&Bs[(wn + ni * 16 + l15) * 64 + rdk[ks]];
#pragma unroll
            for (int ni = 0; ni < 4; ni++)
#pragma unroll
                for (int mi = 0; mi < 2; mi++)
                    acc[mi][ni] = __builtin_amdgcn_mfma_f32_16x16x32_bf16(
                        af[mi], bfr[ni], acc[mi][ni], 0, 0, 0);
        }
    }

#pragma unroll
    for (int ni = 0; ni < 4; ni++) {
        const int n = n0 + wn + ni * 16 + l15;
#pragma unroll
        for (int mi = 0; mi < 2; mi++) {
            const int gm0 = m0 + wm + mi * 16 + quad * 4;
#pragma unroll
            for (int r = 0; r < 4; r++)
                out[(size_t)(gm0 + r) * 1024 + n] = acc[mi][ni][r];
        }
    }
}

// ---------------------------------------------------------------------------
// Flash attention, causal — S^T formulation. R13 kernel UNCHANGED (82.0us):
// two passes {qpair, 31-qpair}, dbuf K+V DMA staging, XCD swizzle, log2-
// domain softmax w/ raw v_exp_f32, defer-max w/ lane-local test, per-lane l
// partial (reduced once/pass), peeled branch-free diagonal, setprio.
// ---------------------------------------------------------------------------
__global__ __launch_bounds__(256, 4)
void attn_k(const ushort* __restrict__ qt, const ushort* __restrict__ kb,
            const ushort* __restrict__ vt, ushort* __restrict__ ao)
{
    __shared__ ushort Ks[2][64 * 64];
    __shared__ ushort Vs[2][64 * 64];   // V^T tile: row = d, col = k_local (swizzled)

    // XCD-aware remap: 1024 blocks -> XCD (lid&7) gets contiguous chunk of 128.
    const int lid = blockIdx.x + blockIdx.y * 16;
    const int nl  = ((lid & 7) << 7) | (lid >> 3);
    const int bh    = nl >> 4;        // 0..63
    const int qpair = nl & 15;        // 0..15
    const int t = threadIdx.x;
    const int lane = t & 63, wv = t >> 6;
    const int l15 = lane & 15, quad = lane >> 4;
    const int b = bh >> 4, h = bh & 15;

    const ushort* kB = kb + (size_t)bh * SEQ * HDIM;
    const ushort* vB = vt + (size_t)bh * HDIM * SEQ;
    const ushort* qB = qt + (size_t)bh * HDIM * SEQ;

    const int rowA = wv * 16 + (lane >> 3);
    const int cg   = (lane & 7) ^ ((lane >> 3) & 7);
    const int koffA = rowA * HDIM + cg * 8;
    const int voffA = rowA * SEQ + cg * 8;

    const int x7 = l15 & 7;
    const int rd0 = l15 * 64 + ((quad ^ x7) * 8);
    const int rd1 = l15 * 64 + (((quad + 4) ^ x7) * 8);

    const int qlo = (quad & 1) * 2;
    const bool hi = (quad >= 2);

#define STAGE(bufi, kt_) do {                                          \
        const int k0_ = (kt_) * 64;                                    \
        ushort* ldsK_ = &Ks[(bufi)][wv * 16 * 64];                     \
        ushort* ldsV_ = &Vs[(bufi)][wv * 16 * 64];                     \
        gl_lds16(kB + (size_t)k0_ * HDIM + koffA,            ldsK_);          \
        gl_lds16(kB + (size_t)k0_ * HDIM + koffA + 8 * HDIM, ldsK_ + 8 * 64); \
        gl_lds16(vB + (size_t)k0_ + voffA,                   ldsV_);          \
        gl_lds16(vB + (size_t)k0_ + voffA + 8 * SEQ,         ldsV_ + 8 * 64); \
    } while (0)

// One attention tile-unit: QK^T (MFMA) -> optional mask -> softmax (log2,
// defer-max, per-lane l partial) -> P pack/redistribute -> PV (MFMA).
#define TILE_UNIT(KSB, VSB, MASKED, KT)  do {                                  \
        f32x4 st[4];                                                           \
        _Pragma("unroll")                                                      \
        for (int mi = 0; mi < 4; mi++) st[mi] = (f32x4){0.f, 0.f, 0.f, 0.f};   \
        __builtin_amdgcn_s_setprio(1);                                         \
        _Pragma("unroll")                                                      \
        for (int mi = 0; mi < 4; mi++) {                                       \
            bf16x8 ka0 = *(const bf16x8*)&(KSB)[mi * 1024 + rd0];              \
            st[mi] = __builtin_amdgcn_mfma_f32_16x16x32_bf16(ka0, qa[0], st[mi], 0, 0, 0); \
        }                                                                      \
        _Pragma("unroll")                                                      \
        for (int mi = 0; mi < 4; mi++) {                                       \
            bf16x8 ka1 = *(const bf16x8*)&(KSB)[mi * 1024 + rd1];              \
            st[mi] = __builtin_amdgcn_mfma_f32_16x16x32_bf16(ka1, qa[1], st[mi], 0, 0, 0); \
        }                                                                      \
        __builtin_amdgcn_s_setprio(0);                                         \
        if (MASKED) {                                                          \
            _Pragma("unroll")                                                  \
            for (int mi = 0; mi < 4; mi++)                                     \
                _Pragma("unroll")                                              \
                for (int r = 0; r < 4; r++) {                                  \
                    int kg = (KT) * 64 + mi * 16 + quad * 4 + r;               \
                    if (kg > qg) st[mi][r] = -30000.f;                         \
                }                                                              \
        }                                                                      \
        const float a0 = max4(st[0][0], st[0][1], st[0][2], st[0][3]);         \
        const float a1 = max4(st[1][0], st[1][1], st[1][2], st[1][3]);         \
        const float a2 = max4(st[2][0], st[2][1], st[2][2], st[2][3]);         \
        const float a3 = max4(st[3][0], st[3][1], st[3][2], st[3][3]);         \
        const float lmax = max4(a0, a1, a2, a3);                               \
        if (!__all(lmax - m <= 11.5415604f)) {                                 \
            float mx = fmaxf(lmax, __shfl_xor(lmax, 16));                      \
            mx = fmaxf(mx, __shfl_xor(mx, 32));                                \
            const float mnew = fmaxf(m, mx);                                   \
            const float alpha = ex2(m - mnew);                                 \
            _Pragma("unroll")                                                  \
            for (int mi = 0; mi < 4; mi++)                                     \
                _Pragma("unroll")                                              \
                for (int r = 0; r < 4; r++) accO[mi][r] *= alpha;              \
            lp *= alpha;                                                       \
            m = mnew;                                                          \
        }                                                                      \
        float s0 = 0.f, s1 = 0.f, s2 = 0.f, s3 = 0.f;                          \
        _Pragma("unroll")                                                      \
        for (int mi = 0; mi < 4; mi++) {                                       \
            float p0 = ex2(st[mi][0] - m);                                     \
            float p1 = ex2(st[mi][1] - m);                                     \
            float p2 = ex2(st[mi][2] - m);                                     \
            float p3 = ex2(st[mi][3] - m);                                     \
            st[mi][0] = p0; st[mi][1] = p1; st[mi][2] = p2; st[mi][3] = p3;    \
            s0 += p0; s1 += p1; s2 += p2; s3 += p3;                            \
        }                                                                      \
        lp += (s0 + s1) + (s2 + s3);                                           \
        uint32_t pr[4][2];                                                     \
        _Pragma("unroll")                                                      \
        for (int mi = 0; mi < 4; mi++) {                                       \
            pr[mi][0] = pk2(st[mi][0], st[mi][1]);                             \
            pr[mi][1] = pk2(st[mi][2], st[mi][3]);                             \
        }                                                                      \
        _Pragma("unroll")                                                      \
        for (int ks2 = 0; ks2 < 2; ks2++) {                                    \
            uint32_t pb[4];                                                    \
            _Pragma("unroll")                                                  \
            for (int w = 0; w < 4; w++) {                                      \
                int srcLane = (qlo + (w >> 1)) * 16 + l15;                     \
                uint32_t va = __shfl(pr[ks2 * 2 + 0][w & 1], srcLane);         \
                uint32_t vb = __shfl(pr[ks2 * 2 + 1][w & 1], srcLane);         \
                pb[w] = hi ? vb : va;                                          \
            }                                                                  \
            bf16x8 pfrag;                                                      \
            *(uint4*)&pfrag = *(uint4*)pb;                                     \
            const int rdv = ks2 ? rd1 : rd0;                                   \
            __builtin_amdgcn_s_setprio(1);                                     \
            _Pragma("unroll")                                                  \
            for (int mi = 0; mi < 4; mi++) {                                   \
                bf16x8 vfr = *(const bf16x8*)&(VSB)[mi * 1024 + rdv];          \
                accO[mi] = __builtin_amdgcn_mfma_f32_16x16x32_bf16(vfr, pfrag, accO[mi], 0, 0, 0); \
            }                                                                  \
            __builtin_amdgcn_s_setprio(0);                                     \
        }                                                                      \
    } while (0)

#pragma unroll 1
    for (int p = 0; p < 2; p++) {
        const int qt_ = p ? (31 - qpair) : qpair;
        const int q0 = qt_ * 64;
        const int qg = q0 + wv * 16 + l15;

        // Q from transposed [bh][d][s]: 16 strided scalar loads, once/pass.
        bf16x8 qa[2];
#pragma unroll
        for (int j = 0; j < 8; j++) {
            qa[0][j] = (short)qB[(size_t)(quad * 8 + j) * SEQ + qg];
            qa[1][j] = (short)qB[(size_t)(32 + quad * 8 + j) * SEQ + qg];
        }

        f32x4 accO[4];
#pragma unroll
        for (int i = 0; i < 4; i++) accO[i] = (f32x4){0.f, 0.f, 0.f, 0.f};
        float m = -30000.f, lp = 0.f;   // lp: per-lane l partial (reduced at end)

        // Pass boundary: all waves done reading prior pass's LDS before the
        // prologue DMA overwrites buf 0.
        __syncthreads();
        STAGE(0, 0);

        // Steady-state: branch-free body, unconditional next-tile STAGE.
#pragma unroll 1
        for (int kt = 0; kt < qt_; kt++) {
            const int buf = kt & 1;
            const ushort* KsB = Ks[buf];
            const ushort* VsB = Vs[buf];
            __syncthreads();               // drains DMA for buf (vmcnt at barrier)
            STAGE(buf ^ 1, kt + 1);        // overlap next tile with compute
            TILE_UNIT(KsB, VsB, false, kt);
        }

        // Peeled diagonal iteration (kt == qt_): causal mask, no prefetch.
        {
            const int buf = qt_ & 1;
            const ushort* KsB = Ks[buf];
            const ushort* VsB = Vs[buf];
            __syncthreads();
            TILE_UNIT(KsB, VsB, true, qt_);
        }

        float lsum = lp;
        lsum += __shfl_xor(lsum, 16);
        lsum += __shfl_xor(lsum, 32);
        const float rl = 1.0f / fmaxf(lsum, 1e-20f);
#pragma unroll
        for (int mi = 0; mi < 4; mi++) {
            uint2 o;
            o.x = pk2(accO[mi][0] * rl, accO[mi][1] * rl);
            o.y = pk2(accO[mi][2] * rl, accO[mi][3] * rl);
            *(uint2*)&ao[((size_t)(b * SEQ + qg)) * D_MODEL + h * HDIM + mi * 16 + quad * 4] = o;
        }
    }
#undef TILE_UNIT
#undef STAGE
}

// ---------------------------------------------------------------------------
extern "C" void kernel_launch(void* const* d_in, const int* in_sizes, int n_in,
                              void* d_out, int out_size, void* d_ws, size_t ws_size,
                              hipStream_t stream)
{
    (void)out_size; (void)ws_size;
    int ix = 0, iwq = 1, iwo = 2;
    for (int i = 0; i < n_in; i++) {
        if (in_sizes[i] == 4 * SEQ * D_MODEL)          ix  = i;  // 8388608
        else if (in_sizes[i] == 3 * D_MODEL * D_MODEL) iwq = i;  // 3145728
        else if (in_sizes[i] == D_MODEL * D_MODEL)     iwo = i;  // 1048576
    }
    const float* X    = (const float*)d_in[ix];
    const float* Wqkv = (const float*)d_in[iwq];
    const float* Wout = (const float*)d_in[iwo];
    float* out = (float*)d_out;

    char* ws = (char*)d_ws;
    const size_t SZ = (size_t)BH * SEQ * HDIM * sizeof(ushort);  // 16.78 MB
    ushort* xb = (ushort*)(ws);            // X in bf16; reused as ao after gemm_qkv
    ushort* qb = (ushort*)(ws + SZ);       // q TRANSPOSED [bh][d][s]
    ushort* kb = (ushort*)(ws + 2 * SZ);
    ushort* vt = (ushort*)(ws + 3 * SZ);
    ushort* wqb = (ushort*)(ws + 4 * SZ);                        // 6.29 MB
    ushort* wob = (ushort*)(ws + 4 * SZ + 3 * (size_t)D_MODEL * D_MODEL * 2);
    ushort* ao = xb;                       // alias: xb dead after gemm_qkv

    cvt_k<<<dim3(6144), 256, 0, stream>>>(X, xb, Wqkv, wqb, Wout, wob);
    gemm_qkv<<<dim3(24, 64), 256, 0, stream>>>(xb, wqb, qb, kb, vt);
    attn_k<<<dim3(16, 64), 256, 0, stream>>>(qb, kb, vt, ao);
    gemm_out<<<dim3(8, 128), 256, 0, stream>>>(ao, wob, out);
}

// Round 15
// 261.836 us; speedup vs baseline: 1.0436x; 1.0436x over previous
//
#include <hip/hip_runtime.h>
#include <hip/hip_bf16.h>
#include <stdint.h>

#define D_MODEL 1024
#define NHEAD   16
#define HDIM    64
#define SEQ     2048
#define BH      64   // 4 batches * 16 heads

typedef short bf16x8 __attribute__((ext_vector_type(8)));
typedef float f32x4  __attribute__((ext_vector_type(4)));

static __device__ __forceinline__ float bf2f(ushort u) {
    union { uint32_t i; float f; } v; v.i = ((uint32_t)u) << 16; return v.f;
}
static __device__ __forceinline__ ushort f2bf(float f) {
    __hip_bfloat16 h = __float2bfloat16(f);
    union { __hip_bfloat16 h; ushort u; } v; v.h = h; return v.u;
}
static __device__ __forceinline__ uint32_t pk2(float a, float b) {
    return (uint32_t)f2bf(a) | ((uint32_t)f2bf(b) << 16);
}
// Raw v_exp_f32 (2^x), single VALU op — NOT libm exp2f (ocml multi-inst).
static __device__ __forceinline__ float ex2(float x) {
    return __builtin_amdgcn_exp2f(x);
}
// Nested for v_max3_f32 fusion.
static __device__ __forceinline__ float max4(float a, float b, float c, float d) {
    return fmaxf(fmaxf(fmaxf(a, b), c), d);
}
// Async global->LDS DMA, 16B per lane; lds dest must be wave-uniform.
static __device__ __forceinline__ void gl_lds16(const ushort* g, ushort* l) {
    __builtin_amdgcn_global_load_lds(
        (const __attribute__((address_space(1))) uint32_t*)g,
        (__attribute__((address_space(3))) uint32_t*)l, 16, 0, 0);
}

// ---------------------------------------------------------------------------
// fp32 -> bf16 pre-convert (RNE), 8 elems/thread. Three source buffers fused
// into one launch (block ranges: X | Wqkv | Wout).
// ---------------------------------------------------------------------------
__global__ __launch_bounds__(256)
void cvt_k(const float* __restrict__ s0, ushort* __restrict__ d0,
           const float* __restrict__ s1, ushort* __restrict__ d1,
           const float* __restrict__ s2, ushort* __restrict__ d2)
{
    int blk = blockIdx.x;
    const float* src; ushort* dst;
    if (blk < 4096)      { src = s0; dst = d0; }
    else if (blk < 5632) { src = s1; dst = d1; blk -= 4096; }
    else                 { src = s2; dst = d2; blk -= 5632; }
    const size_t i = ((size_t)blk * 256 + threadIdx.x) * 8;
    float4 a = *(const float4*)&src[i];
    float4 b = *(const float4*)&src[i + 4];
    uint4 o;
    o.x = pk2(a.x, a.y);
    o.y = pk2(a.z, a.w);
    o.z = pk2(b.x, b.y);
    o.w = pk2(b.z, b.w);
    *(uint4*)&dst[i] = o;
}

// ---------------------------------------------------------------------------
// GEMM1: qkv = Xb[8192,1024](bf16) * Wb[3072,1024](bf16)^T.
// Staging via global_load_lds DMA, XOR-swizzled unpadded 64-stride rows.
// XCD-swizzled block mapping (m-panel-grouped). RoPE fused in epilogue (r14).
// r16: q pre-scale folds log2(e) => attn softmax in log2 domain.
// r18: q stored TRANSPOSED [bh][d][s].
// r20: RoPE epilogue via angle-addition recurrence (kept in r21 — pure VALU
// shave; the r20 gemm_out retile was the regression and is reverted).
// ---------------------------------------------------------------------------
__global__ __launch_bounds__(256)
void gemm_qkv(const ushort* __restrict__ Xb, const ushort* __restrict__ Wb,
              ushort* __restrict__ qt, ushort* __restrict__ kb,
              ushort* __restrict__ vt)
{
    __shared__ ushort As[128 * 64];
    __shared__ ushort Bs[128 * 64];
    const int K = 1024;
    const int lid = blockIdx.x + blockIdx.y * 24;
    const int nl  = (lid & 7) * 192 + (lid >> 3);
    const int n0 = (nl % 24) * 128;
    const int m0 = (nl / 24) * 128;
    const int t = threadIdx.x;
    const int lane = t & 63, wv = t >> 6;
    const int wm = (wv >> 1) * 64, wn = (wv & 1) * 64;
    const int l15 = lane & 15, quad = lane >> 4;

    const int rsub = lane >> 3;
    const int cg   = (lane & 7) ^ rsub;            // swizzled global chunk
    const int x7  = l15 & 7;
    const int rdk[2] = { ((quad ^ x7) * 8), (((quad + 4) ^ x7) * 8) };

    f32x4 acc[4][4];
#pragma unroll
    for (int i = 0; i < 4; i++)
#pragma unroll
        for (int j = 0; j < 4; j++) acc[i][j] = (f32x4){0.f, 0.f, 0.f, 0.f};

    for (int k0 = 0; k0 < K; k0 += 64) {
        __syncthreads();
#pragma unroll
        for (int i = 0; i < 4; i++) {
            const int rbase = i * 32 + wv * 8;
            gl_lds16(&Xb[(size_t)(m0 + rbase + rsub) * K + k0 + cg * 8], &As[rbase * 64]);
            gl_lds16(&Wb[(size_t)(n0 + rbase + rsub) * K + k0 + cg * 8], &Bs[rbase * 64]);
        }
        __syncthreads();
#pragma unroll
        for (int ks = 0; ks < 2; ks++) {
            bf16x8 af[4], bfr[4];
#pragma unroll
            for (int mi = 0; mi < 4; mi++)
                af[mi] = *(const bf16x8*)&As[(wm + mi * 16 + l15) * 64 + rdk[ks]];
#pragma unroll
            for (int ni = 0; ni < 4; ni++)
                bfr[ni] = *(const bf16x8*)&Bs[(wn + ni * 16 + l15) * 64 + rdk[ks]];
#pragma unroll
            for (int ni = 0; ni < 4; ni++)
#pragma unroll
                for (int mi = 0; mi < 4; mi++)
                    acc[mi][ni] = __builtin_amdgcn_mfma_f32_16x16x32_bf16(
                        af[mi], bfr[ni], acc[mi][ni], 0, 0, 0);
        }
    }

#pragma unroll
    for (int ni = 0; ni < 4; ni++) {
        const int e = n0 + wn + ni * 16 + l15;
        const int which = e >> 10;     // block-uniform (tiles don't straddle)
        const int h = (e >> 6) & 15;
        const int d = e & 63;
#pragma unroll
        for (int mi = 0; mi < 4; mi++) {
            const int gm0 = m0 + wm + mi * 16 + quad * 4;
            const int b = gm0 >> 11;
            const int s0 = gm0 & 2047;
            const int bh = b * NHEAD + h;
            if (which == 2) {
                ushort4 pk;
                pk.x = f2bf(acc[mi][ni][0]); pk.y = f2bf(acc[mi][ni][1]);
                pk.z = f2bf(acc[mi][ni][2]); pk.w = f2bf(acc[mi][ni][3]);
                *(ushort4*)&vt[((size_t)bh * HDIM + d) * SEQ + s0] = pk;
            } else {
                // RoPE: freq = 10000^{-(d>>1)/32}; partner x[d^1] from lane^1.
                const float freq = __expf(-(float)(d >> 1) * (9.2103403719761836f / 32.0f));
                const float sgn = (d & 1) ? 1.0f : -1.0f;
                float cf, sf;                       // sincos(freq) — CSE'd per d
                __sincosf(freq, &sf, &cf);
                float sn, cs;                       // sincos(s0*freq), advanced by r
                __sincosf((float)s0 * freq, &sn, &cs);
                float o[4];
#pragma unroll
                for (int r = 0; r < 4; r++) {
                    const float v = acc[mi][ni][r];
                    const float p = __shfl_xor(v, 1);
                    o[r] = v * cs + sgn * p * sn;
                    const float cs2 = cs * cf - sn * sf;   // exact rotation by freq
                    sn = sn * cf + cs * sf;
                    cs = cs2;
                }
                if (which == 0) {
                    // q: 1/sqrt(64)*log2(e) folded; transposed [bh][d][s] store.
                    ushort4 pk;
                    pk.x = f2bf(o[0] * 0.18033688f); pk.y = f2bf(o[1] * 0.18033688f);
                    pk.z = f2bf(o[2] * 0.18033688f); pk.w = f2bf(o[3] * 0.18033688f);
                    *(ushort4*)&qt[((size_t)bh * HDIM + d) * SEQ + s0] = pk;
                } else {
#pragma unroll
                    for (int r = 0; r < 4; r++)
                        kb[((size_t)bh * SEQ + s0 + r) * HDIM + d] = f2bf(o[r]);
                }
            }
        }
    }
}

// ---------------------------------------------------------------------------
// GEMM2: out(f32) = A[8192,1024](bf16) * Wb[1024,1024](bf16)^T — DMA staging.
// REVERTED to 128x128 tile (r20's 64x128 retile regressed ~10us: compute:
// stage ratio worsened 2:1 -> 1.33:1 and B-panel staging traffic doubled).
// XCD-swizzled block mapping (m-panel-grouped).
// ---------------------------------------------------------------------------
__global__ __launch_bounds__(256)
void gemm_out(const ushort* __restrict__ A, const ushort* __restrict__ Wb,
              float* __restrict__ out)
{
    __shared__ ushort As[128 * 64];
    __shared__ ushort Bs[128 * 64];
    const int K = 1024;
    const int lid = blockIdx.x + blockIdx.y * 8;
    const int nl  = (lid & 7) * 64 + (lid >> 3);
    const int n0 = (nl & 7) * 128;
    const int m0 = (nl >> 3) * 128;
    const int t = threadIdx.x;
    const int lane = t & 63, wv = t >> 6;
    const int wm = (wv >> 1) * 64, wn = (wv & 1) * 64;
    const int l15 = lane & 15, quad = lane >> 4;

    const int rsub = lane >> 3;
    const int cg   = (lane & 7) ^ rsub;
    const int x7  = l15 & 7;
    const int rdk[2] = { ((quad ^ x7) * 8), (((quad + 4) ^ x7) * 8) };

    f32x4 acc[4][4];
#pragma unroll
    for (int i = 0; i < 4; i++)
#pragma unroll
        for (int j = 0; j < 4; j++) acc[i][j] = (f32x4){0.f, 0.f, 0.f, 0.f};

    for (int k0 = 0; k0 < K; k0 += 64) {
        __syncthreads();
#pragma unroll
        for (int i = 0; i < 4; i++) {
            const int rbase = i * 32 + wv * 8;
            gl_lds16(&A[(size_t)(m0 + rbase + rsub) * K + k0 + cg * 8],  &As[rbase * 64]);
            gl_lds16(&Wb[(size_t)(n0 + rbase + rsub) * K + k0 + cg * 8], &Bs[rbase * 64]);
        }
        __syncthreads();
#pragma unroll
        for (int ks = 0; ks < 2; ks++) {
            bf16x8 af[4], bfr[4];
#pragma unroll
            for (int mi = 0; mi < 4; mi++)
                af[mi] = *(const bf16x8*)&As[(wm + mi * 16 + l15) * 64 + rdk[ks]];
#pragma unroll
            for (int ni = 0; ni < 4; ni++)
                bfr[ni] = *(const bf16x8*)&Bs[(wn + ni * 16 + l15) * 64 + rdk[ks]];
#pragma unroll
            for (int ni = 0; ni < 4; ni++)
#pragma unroll
                for (int mi = 0; mi < 4; mi++)
                    acc[mi][ni] = __builtin_amdgcn_mfma_f32_16x16x32_bf16(
                        af[mi], bfr[ni], acc[mi][ni], 0, 0, 0);
        }
    }

#pragma unroll
    for (int ni = 0; ni < 4; ni++) {
        const int n = n0 + wn + ni * 16 + l15;
#pragma unroll
        for (int mi = 0; mi < 4; mi++) {
            const int gm0 = m0 + wm + mi * 16 + quad * 4;
#pragma unroll
            for (int r = 0; r < 4; r++)
                out[(size_t)(gm0 + r) * 1024 + n] = acc[mi][ni][r];
        }
    }
}

// ---------------------------------------------------------------------------
// Flash attention, causal — S^T formulation. R13 kernel UNCHANGED (82.0us):
// two passes {qpair, 31-qpair}, dbuf K+V DMA staging, XCD swizzle, log2-
// domain softmax w/ raw v_exp_f32, defer-max w/ lane-local test, per-lane l
// partial (reduced once/pass), peeled branch-free diagonal, setprio.
// ---------------------------------------------------------------------------
__global__ __launch_bounds__(256, 4)
void attn_k(const ushort* __restrict__ qt, const ushort* __restrict__ kb,
            const ushort* __restrict__ vt, ushort* __restrict__ ao)
{
    __shared__ ushort Ks[2][64 * 64];
    __shared__ ushort Vs[2][64 * 64];   // V^T tile: row = d, col = k_local (swizzled)

    // XCD-aware remap: 1024 blocks -> XCD (lid&7) gets contiguous chunk of 128.
    const int lid = blockIdx.x + blockIdx.y * 16;
    const int nl  = ((lid & 7) << 7) | (lid >> 3);
    const int bh    = nl >> 4;        // 0..63
    const int qpair = nl & 15;        // 0..15
    const int t = threadIdx.x;
    const int lane = t & 63, wv = t >> 6;
    const int l15 = lane & 15, quad = lane >> 4;
    const int b = bh >> 4, h = bh & 15;

    const ushort* kB = kb + (size_t)bh * SEQ * HDIM;
    const ushort* vB = vt + (size_t)bh * HDIM * SEQ;
    const ushort* qB = qt + (size_t)bh * HDIM * SEQ;

    const int rowA = wv * 16 + (lane >> 3);
    const int cg   = (lane & 7) ^ ((lane >> 3) & 7);
    const int koffA = rowA * HDIM + cg * 8;
    const int voffA = rowA * SEQ + cg * 8;

    const int x7 = l15 & 7;
    const int rd0 = l15 * 64 + ((quad ^ x7) * 8);
    const int rd1 = l15 * 64 + (((quad + 4) ^ x7) * 8);

    const int qlo = (quad & 1) * 2;
    const bool hi = (quad >= 2);

#define STAGE(bufi, kt_) do {                                          \
        const int k0_ = (kt_) * 64;                                    \
        ushort* ldsK_ = &Ks[(bufi)][wv * 16 * 64];                     \
        ushort* ldsV_ = &Vs[(bufi)][wv * 16 * 64];                     \
        gl_lds16(kB + (size_t)k0_ * HDIM + koffA,            ldsK_);          \
        gl_lds16(kB + (size_t)k0_ * HDIM + koffA + 8 * HDIM, ldsK_ + 8 * 64); \
        gl_lds16(vB + (size_t)k0_ + voffA,                   ldsV_);          \
        gl_lds16(vB + (size_t)k0_ + voffA + 8 * SEQ,         ldsV_ + 8 * 64); \
    } while (0)

// One attention tile-unit: QK^T (MFMA) -> optional mask -> softmax (log2,
// defer-max, per-lane l partial) -> P pack/redistribute -> PV (MFMA).
#define TILE_UNIT(KSB, VSB, MASKED, KT)  do {                                  \
        f32x4 st[4];                                                           \
        _Pragma("unroll")                                                      \
        for (int mi = 0; mi < 4; mi++) st[mi] = (f32x4){0.f, 0.f, 0.f, 0.f};   \
        __builtin_amdgcn_s_setprio(1);                                         \
        _Pragma("unroll")                                                      \
        for (int mi = 0; mi < 4; mi++) {                                       \
            bf16x8 ka0 = *(const bf16x8*)&(KSB)[mi * 1024 + rd0];              \
            st[mi] = __builtin_amdgcn_mfma_f32_16x16x32_bf16(ka0, qa[0], st[mi], 0, 0, 0); \
        }                                                                      \
        _Pragma("unroll")                                                      \
        for (int mi = 0; mi < 4; mi++) {                                       \
            bf16x8 ka1 = *(const bf16x8*)&(KSB)[mi * 1024 + rd1];              \
            st[mi] = __builtin_amdgcn_mfma_f32_16x16x32_bf16(ka1, qa[1], st[mi], 0, 0, 0); \
        }                                                                      \
        __builtin_amdgcn_s_setprio(0);                                         \
        if (MASKED) {                                                          \
            _Pragma("unroll")                                                  \
            for (int mi = 0; mi < 4; mi++)                                     \
                _Pragma("unroll")                                              \
                for (int r = 0; r < 4; r++) {                                  \
                    int kg = (KT) * 64 + mi * 16 + quad * 4 + r;               \
                    if (kg > qg) st[mi][r] = -30000.f;                         \
                }                                                              \
        }                                                                      \
        const float a0 = max4(st[0][0], st[0][1], st[0][2], st[0][3]);         \
        const float a1 = max4(st[1][0], st[1][1], st[1][2], st[1][3]);         \
        const float a2 = max4(st[2][0], st[2][1], st[2][2], st[2][3]);         \
        const float a3 = max4(st[3][0], st[3][1], st[3][2], st[3][3]);         \
        const float lmax = max4(a0, a1, a2, a3);                               \
        if (!__all(lmax - m <= 11.5415604f)) {                                 \
            float mx = fmaxf(lmax, __shfl_xor(lmax, 16));                      \
            mx = fmaxf(mx, __shfl_xor(mx, 32));                                \
            const float mnew = fmaxf(m, mx);                                   \
            const float alpha = ex2(m - mnew);                                 \
            _Pragma("unroll")                                                  \
            for (int mi = 0; mi < 4; mi++)                                     \
                _Pragma("unroll")                                              \
                for (int r = 0; r < 4; r++) accO[mi][r] *= alpha;              \
            lp *= alpha;                                                       \
            m = mnew;                                                          \
        }                                                                      \
        float s0 = 0.f, s1 = 0.f, s2 = 0.f, s3 = 0.f;                          \
        _Pragma("unroll")                                                      \
        for (int mi = 0; mi < 4; mi++) {                                       \
            float p0 = ex2(st[mi][0] - m);                                     \
            float p1 = ex2(st[mi][1] - m);                                     \
            float p2 = ex2(st[mi][2] - m);                                     \
            float p3 = ex2(st[mi][3] - m);                                     \
            st[mi][0] = p0; st[mi][1] = p1; st[mi][2] = p2; st[mi][3] = p3;    \
            s0 += p0; s1 += p1; s2 += p2; s3 += p3;                            \
        }                                                                      \
        lp += (s0 + s1) + (s2 + s3);                                           \
        uint32_t pr[4][2];                                                     \
        _Pragma("unroll")                                                      \
        for (int mi = 0; mi < 4; mi++) {                                       \
            pr[mi][0] = pk2(st[mi][0], st[mi][1]);                             \
            pr[mi][1] = pk2(st[mi][2], st[mi][3]);                             \
        }                                                                      \
        _Pragma("unroll")                                                      \
        for (int ks2 = 0; ks2 < 2; ks2++) {                                    \
            uint32_t pb[4];                                                    \
            _Pragma("unroll")                                                  \
            for (int w = 0; w < 4; w++) {                                      \
                int srcLane = (qlo + (w >> 1)) * 16 + l15;                     \
                uint32_t va = __shfl(pr[ks2 * 2 + 0][w & 1], srcLane);         \
                uint32_t vb = __shfl(pr[ks2 * 2 + 1][w & 1], srcLane);         \
                pb[w] = hi ? vb : va;                                          \
            }                                                                  \
            bf16x8 pfrag;                                                      \
            *(uint4*)&pfrag = *(uint4*)pb;                                     \
            const int rdv = ks2 ? rd1 : rd0;                                   \
            __builtin_amdgcn_s_setprio(1);                                     \
            _Pragma("unroll")                                                  \
            for (int mi = 0; mi < 4; mi++) {                                   \
                bf16x8 vfr = *(const bf16x8*)&(VSB)[mi * 1024 + rdv];          \
                accO[mi] = __builtin_amdgcn_mfma_f32_16x16x32_bf16(vfr, pfrag, accO[mi], 0, 0, 0); \
            }                                                                  \
            __builtin_amdgcn_s_setprio(0);                                     \
        }                                                                      \
    } while (0)

#pragma unroll 1
    for (int p = 0; p < 2; p++) {
        const int qt_ = p ? (31 - qpair) : qpair;
        const int q0 = qt_ * 64;
        const int qg = q0 + wv * 16 + l15;

        // Q from transposed [bh][d][s]: 16 strided scalar loads, once/pass.
        bf16x8 qa[2];
#pragma unroll
        for (int j = 0; j < 8; j++) {
            qa[0][j] = (short)qB[(size_t)(quad * 8 + j) * SEQ + qg];
            qa[1][j] = (short)qB[(size_t)(32 + quad * 8 + j) * SEQ + qg];
        }

        f32x4 accO[4];
#pragma unroll
        for (int i = 0; i < 4; i++) accO[i] = (f32x4){0.f, 0.f, 0.f, 0.f};
        float m = -30000.f, lp = 0.f;   // lp: per-lane l partial (reduced at end)

        // Pass boundary: all waves done reading prior pass's LDS before the
        // prologue DMA overwrites buf 0.
        __syncthreads();
        STAGE(0, 0);

        // Steady-state: branch-free body, unconditional next-tile STAGE.
#pragma unroll 1
        for (int kt = 0; kt < qt_; kt++) {
            const int buf = kt & 1;
            const ushort* KsB = Ks[buf];
            const ushort* VsB = Vs[buf];
            __syncthreads();               // drains DMA for buf (vmcnt at barrier)
            STAGE(buf ^ 1, kt + 1);        // overlap next tile with compute
            TILE_UNIT(KsB, VsB, false, kt);
        }

        // Peeled diagonal iteration (kt == qt_): causal mask, no prefetch.
        {
            const int buf = qt_ & 1;
            const ushort* KsB = Ks[buf];
            const ushort* VsB = Vs[buf];
            __syncthreads();
            TILE_UNIT(KsB, VsB, true, qt_);
        }

        float lsum = lp;
        lsum += __shfl_xor(lsum, 16);
        lsum += __shfl_xor(lsum, 32);
        const float rl = 1.0f / fmaxf(lsum, 1e-20f);
#pragma unroll
        for (int mi = 0; mi < 4; mi++) {
            uint2 o;
            o.x = pk2(accO[mi][0] * rl, accO[mi][1] * rl);
            o.y = pk2(accO[mi][2] * rl, accO[mi][3] * rl);
            *(uint2*)&ao[((size_t)(b * SEQ + qg)) * D_MODEL + h * HDIM + mi * 16 + quad * 4] = o;
        }
    }
#undef TILE_UNIT
#undef STAGE
}

// ---------------------------------------------------------------------------
extern "C" void kernel_launch(void* const* d_in, const int* in_sizes, int n_in,
                              void* d_out, int out_size, void* d_ws, size_t ws_size,
                              hipStream_t stream)
{
    (void)out_size; (void)ws_size;
    int ix = 0, iwq = 1, iwo = 2;
    for (int i = 0; i < n_in; i++) {
        if (in_sizes[i] == 4 * SEQ * D_MODEL)          ix  = i;  // 8388608
        else if (in_sizes[i] == 3 * D_MODEL * D_MODEL) iwq = i;  // 3145728
        else if (in_sizes[i] == D_MODEL * D_MODEL)     iwo = i;  // 1048576
    }
    const float* X    = (const float*)d_in[ix];
    const float* Wqkv = (const float*)d_in[iwq];
    const float* Wout = (const float*)d_in[iwo];
    float* out = (float*)d_out;

    char* ws = (char*)d_ws;
    const size_t SZ = (size_t)BH * SEQ * HDIM * sizeof(ushort);  // 16.78 MB
    ushort* xb = (ushort*)(ws);            // X in bf16; reused as ao after gemm_qkv
    ushort* qb = (ushort*)(ws + SZ);       // q TRANSPOSED [bh][d][s]
    ushort* kb = (ushort*)(ws + 2 * SZ);
    ushort* vt = (ushort*)(ws + 3 * SZ);
    ushort* wqb = (ushort*)(ws + 4 * SZ);                        // 6.29 MB
    ushort* wob = (ushort*)(ws + 4 * SZ + 3 * (size_t)D_MODEL * D_MODEL * 2);
    ushort* ao = xb;                       // alias: xb dead after gemm_qkv

    cvt_k<<<dim3(6144), 256, 0, stream>>>(X, xb, Wqkv, wqb, Wout, wob);
    gemm_qkv<<<dim3(24, 64), 256, 0, stream>>>(xb, wqb, qb, kb, vt);
    attn_k<<<dim3(16, 64), 256, 0, stream>>>(qb, kb, vt, ao);
    gemm_out<<<dim3(8, 64), 256, 0, stream>>>(ao, wob, out);
}